// Round 14
// baseline (707.199 us; speedup 1.0000x reference)
//
#include <hip/hip_runtime.h>

#define N_NODES 50000
#define N_EDGES 800000
#define NGRAPH 512
#define MAXDEG 64
#define BN_EPS 1e-5f
#define NTILES 3125   // 50000/16 exactly
#define NPB 500       // nodes per fill block
#define FBLOCKS 100   // ceil(50000/500)

typedef __attribute__((ext_vector_type(8))) short s16x8;
typedef __attribute__((ext_vector_type(4))) float f32x4;

__device__ __forceinline__ ushort bf16_rne(float f) {
  uint u = __float_as_uint(f);
  return (ushort)((u + 0x7FFFu + ((u >> 16) & 1u)) >> 16);
}
__device__ __forceinline__ void bf16split(float f, ushort& h, ushort& l) {
  uint u = __float_as_uint(f);
  uint hb = (u + 0x7FFFu + ((u >> 16) & 1u)) & 0xFFFF0000u;
  h = (ushort)(hb >> 16);
  l = bf16_rne(f - __uint_as_float(hb));
}
__device__ __forceinline__ float bf16f(ushort h) {
  return __uint_as_float(((uint)h) << 16);
}

// ---------------- CSR build: dst-partitioned, LDS cursors, dense writes ------
// Each block owns dst range [blockIdx*NPB, +NPB): streams the dst array
// (L2-broadcast), slots via LDS atomics, csr writes stay in a 64KB region.
// Final cursors are the degrees -> no separate hist pass.
__global__ __launch_bounds__(512) void fill2_kernel(
    const int* __restrict__ ei, ushort* __restrict__ csr, int* __restrict__ deg)
{
  __shared__ int curs[NPB];
  int tid = threadIdx.x;
  int lo = blockIdx.x * NPB;
  int hi = min(lo + NPB, N_NODES);
  for (int i = tid; i < NPB; i += 512) curs[i] = 0;
  __syncthreads();
  const int* dstp = ei + N_EDGES;
  for (int e = tid; e < N_EDGES; e += 512) {
    int dst = dstp[e];
    if (dst >= lo && dst < hi) {
      int slot = atomicAdd(&curs[dst - lo], 1);
      if (slot < MAXDEG) csr[dst * MAXDEG + slot] = (ushort)ei[e];
    }
  }
  __syncthreads();
  for (int i = tid; i < hi - lo; i += 512) deg[lo + i] = curs[i];
}

// ---------------- weight pre-pack: f32 [wl;wr] -> frag-ordered bf16 hi/lo ----
__global__ __launch_bounds__(256) void wpack_kernel(
    const float* __restrict__ w1l, const float* __restrict__ w1r,
    const float* __restrict__ w2l, const float* __restrict__ w2r,
    ushort* __restrict__ Wph, ushort* __restrict__ Wpl)
{
  int idx = blockIdx.x * 256 + threadIdx.x;   // < 65536
  int layer = idx >> 15;
  int e = idx & 32767;
  int j = e & 7, l = (e >> 3) & 63, t = (e >> 9) & 7, s = e >> 12;
  int k = s * 32 + ((l >> 4) << 3) + j;
  int col = t * 16 + (l & 15);
  const float* wl = layer ? w2l : w1l;
  const float* wr = layer ? w2r : w1r;
  float w = (k < 128) ? wl[k * 128 + col] : wr[(k - 128) * 128 + col];
  ushort h, lo;
  bf16split(w, h, lo);
  Wph[idx] = h;
  Wpl[idx] = lo;
}

// ---------------- split x (f32 -> bf16 hi/lo) into A[:,128:256] --------------
__global__ __launch_bounds__(256) void splitx_kernel(
    const float* __restrict__ x, ushort* __restrict__ Ahi, ushort* __restrict__ Alo)
{
  int i = blockIdx.x * 256 + threadIdx.x;
  if (i >= N_NODES * 32) return;
  int n = i >> 5, j = i & 31;
  float4 v = ((const float4*)x)[i];
  ushort4 h, l;
  bf16split(v.x, h.x, l.x); bf16split(v.y, h.y, l.y);
  bf16split(v.z, h.z, l.z); bf16split(v.w, h.w, l.w);
  *(ushort4*)(Ahi + (size_t)n * 256 + 128 + j * 4) = h;
  *(ushort4*)(Alo + (size_t)n * 256 + 128 + j * 4) = l;
}

// ---------------- gather: mean of bf16-hi rows A[:,128:256) -> A[:,0:128) ----
__global__ __launch_bounds__(256) void gather_kernel(
    ushort* Ahi, ushort* Alo,
    const ushort* __restrict__ csr, const int* __restrict__ deg)
{
  int gid = blockIdx.x * 256 + threadIdx.x;
  int n = gid >> 5, j = gid & 31;
  if (n >= N_NODES) return;
  int d = min(deg[n], MAXDEG);
  const ushort* lst = csr + n * MAXDEG;
  float ax = 0, ay = 0, az = 0, aw = 0;
  int i = 0;
  for (; i + 4 <= d; i += 4) {
    int s0 = lst[i], s1 = lst[i + 1], s2 = lst[i + 2], s3 = lst[i + 3];
    ushort4 h0 = *(const ushort4*)(Ahi + (size_t)s0 * 256 + 128 + j * 4);
    ushort4 h1 = *(const ushort4*)(Ahi + (size_t)s1 * 256 + 128 + j * 4);
    ushort4 h2 = *(const ushort4*)(Ahi + (size_t)s2 * 256 + 128 + j * 4);
    ushort4 h3 = *(const ushort4*)(Ahi + (size_t)s3 * 256 + 128 + j * 4);
    ax += (bf16f(h0.x) + bf16f(h1.x)) + (bf16f(h2.x) + bf16f(h3.x));
    ay += (bf16f(h0.y) + bf16f(h1.y)) + (bf16f(h2.y) + bf16f(h3.y));
    az += (bf16f(h0.z) + bf16f(h1.z)) + (bf16f(h2.z) + bf16f(h3.z));
    aw += (bf16f(h0.w) + bf16f(h1.w)) + (bf16f(h2.w) + bf16f(h3.w));
  }
  for (; i < d; ++i) {
    ushort4 h = *(const ushort4*)(Ahi + (size_t)lst[i] * 256 + 128 + j * 4);
    ax += bf16f(h.x); ay += bf16f(h.y); az += bf16f(h.z); aw += bf16f(h.w);
  }
  float inv = 1.0f / fmaxf((float)d, 1.0f);
  ax *= inv; ay *= inv; az *= inv; aw *= inv;
  ushort4 h, l;
  bf16split(ax, h.x, l.x); bf16split(ay, h.y, l.y);
  bf16split(az, h.z, l.z); bf16split(aw, h.w, l.w);
  *(ushort4*)(Ahi + (size_t)n * 256 + j * 4) = h;
  *(ushort4*)(Alo + (size_t)n * 256 + j * 4) = l;
}

// ---------------- MFMA GEMM: z = A(hi+lo) @ W(hi+lo) + b; BN stats -----------
__global__ __launch_bounds__(512) void gemm_kernel(
    const ushort* __restrict__ Ahi, const ushort* __restrict__ Alo,
    const ushort* __restrict__ Wph, const ushort* __restrict__ Wpl,
    const float* __restrict__ bias,
    float* __restrict__ z, float* __restrict__ stats)
{
  __shared__ uint4 lds_w[8192];           // 128 KB: [0:4096) hi, [4096:8192) lo
  __shared__ float lds_stats[256];
  int tid = threadIdx.x;

  { // coalesced vector staging of pre-packed fragments
    const uint4* gh = (const uint4*)Wph;
    const uint4* gl = (const uint4*)Wpl;
    #pragma unroll
    for (int i = 0; i < 8; ++i) lds_w[tid + i * 512] = gh[tid + i * 512];
    #pragma unroll
    for (int i = 0; i < 8; ++i) lds_w[4096 + tid + i * 512] = gl[tid + i * 512];
  }
  if (tid < 256) lds_stats[tid] = 0.f;
  __syncthreads();

  int wave = tid >> 6, lane = tid & 63;
  int col0 = lane & 15, rg = lane >> 4;
  int t0 = blockIdx.x * 16 + wave * 2;      // first tile of this wave
  bool v0 = t0 < NTILES, v1 = (t0 + 1) < NTILES;
  int r0 = min(t0 * 16 + col0, N_NODES - 1);        // clamped: no OOB loads
  int r1 = min(t0 * 16 + 16 + col0, N_NODES - 1);

  const s16x8* W8h = (const s16x8*)lds_w;
  const s16x8* W8l = W8h + 4096;
  const s16x8* pah0 = (const s16x8*)Ahi + (size_t)r0 * 32 + rg;
  const s16x8* pal0 = (const s16x8*)Alo + (size_t)r0 * 32 + rg;
  const s16x8* pah1 = (const s16x8*)Ahi + (size_t)r1 * 32 + rg;
  const s16x8* pal1 = (const s16x8*)Alo + (size_t)r1 * 32 + rg;

  f32x4 acc0[8], acc1[8];
  #pragma unroll
  for (int t = 0; t < 8; ++t) {
    float bc = bias[t * 16 + col0];
    acc0[t] = (f32x4){bc, bc, bc, bc};
    acc1[t] = acc0[t];
  }

  for (int s = 0; s < 8; ++s) {
    s16x8 ah0 = pah0[s * 4];
    s16x8 al0 = pal0[s * 4];
    s16x8 ah1 = pah1[s * 4];
    s16x8 al1 = pal1[s * 4];
    #pragma unroll
    for (int t = 0; t < 8; ++t) {
      s16x8 wh = W8h[(s * 8 + t) * 64 + lane];
      s16x8 wo = W8l[(s * 8 + t) * 64 + lane];
      acc0[t] = __builtin_amdgcn_mfma_f32_16x16x32_bf16(ah0, wh, acc0[t], 0, 0, 0);
      acc0[t] = __builtin_amdgcn_mfma_f32_16x16x32_bf16(al0, wh, acc0[t], 0, 0, 0);
      acc0[t] = __builtin_amdgcn_mfma_f32_16x16x32_bf16(ah0, wo, acc0[t], 0, 0, 0);
      acc1[t] = __builtin_amdgcn_mfma_f32_16x16x32_bf16(ah1, wh, acc1[t], 0, 0, 0);
      acc1[t] = __builtin_amdgcn_mfma_f32_16x16x32_bf16(al1, wh, acc1[t], 0, 0, 0);
      acc1[t] = __builtin_amdgcn_mfma_f32_16x16x32_bf16(ah1, wo, acc1[t], 0, 0, 0);
    }
  }

  // epilogue: C/D layout col=lane&15, row=(lane>>4)*4+reg
  float psum[8], psq[8];
  #pragma unroll
  for (int t = 0; t < 8; ++t) { psum[t] = 0.f; psq[t] = 0.f; }
  if (v0) {
    #pragma unroll
    for (int t = 0; t < 8; ++t) {
      #pragma unroll
      for (int r = 0; r < 4; ++r) {
        float v = acc0[t][r];
        z[(size_t)(t0 * 16 + rg * 4 + r) * 128 + t * 16 + col0] = v;
        psum[t] += v; psq[t] += v * v;
      }
    }
  }
  if (v1) {
    #pragma unroll
    for (int t = 0; t < 8; ++t) {
      #pragma unroll
      for (int r = 0; r < 4; ++r) {
        float v = acc1[t][r];
        z[(size_t)(t0 * 16 + 16 + rg * 4 + r) * 128 + t * 16 + col0] = v;
        psum[t] += v; psq[t] += v * v;
      }
    }
  }

  #pragma unroll
  for (int t = 0; t < 8; ++t) {
    atomicAdd(&lds_stats[t * 16 + col0], psum[t]);
    atomicAdd(&lds_stats[128 + t * 16 + col0], psq[t]);
  }
  __syncthreads();
  if (tid < 256) atomicAdd(&stats[tid], lds_stats[tid]);
}

// ---------------- BN finalize ----------------
__global__ __launch_bounds__(128) void finalize_kernel(
    const float* __restrict__ stats, const float* __restrict__ gamma,
    const float* __restrict__ beta, float* __restrict__ scsh)
{
  int f = threadIdx.x;
  const float invN = 1.0f / (float)N_NODES;
  float mu = stats[f] * invN;
  float var = stats[128 + f] * invN - mu * mu;
  var = fmaxf(var, 0.f);
  float s = gamma[f] * rsqrtf(var + BN_EPS);
  scsh[f] = s;
  scsh[128 + f] = beta[f] - mu * s;
}

// ---------------- BN+relu -> bf16 pair into A[:,128:256] (layer-1 h) --------
__global__ __launch_bounds__(256) void bnrelu_split_kernel(
    const float* __restrict__ z, const float* __restrict__ scsh,
    ushort* __restrict__ Ahi, ushort* __restrict__ Alo)
{
  const float4* sc4 = (const float4*)scsh;
  const float4* sh4 = (const float4*)(scsh + 128);
  int i = blockIdx.x * 256 + threadIdx.x;
  if (i >= N_NODES * 32) return;
  int n = i >> 5, c4 = i & 31;
  float4 v = ((const float4*)z)[i];
  float4 s = sc4[c4], hh = sh4[c4];
  v.x = fmaxf(0.f, fmaf(v.x, s.x, hh.x));
  v.y = fmaxf(0.f, fmaf(v.y, s.y, hh.y));
  v.z = fmaxf(0.f, fmaf(v.z, s.z, hh.z));
  v.w = fmaxf(0.f, fmaf(v.w, s.w, hh.w));
  ushort4 h, l;
  bf16split(v.x, h.x, l.x); bf16split(v.y, h.y, l.y);
  bf16split(v.z, h.z, l.z); bf16split(v.w, h.w, l.w);
  *(ushort4*)(Ahi + (size_t)n * 256 + 128 + c4 * 4) = h;
  *(ushort4*)(Alo + (size_t)n * 256 + 128 + c4 * 4) = l;
}

// ---------------- BN+relu in place f32 (layer-2 h, feeds pool) ---------------
__global__ __launch_bounds__(256) void bnrelu_kernel(
    float* __restrict__ z, const float* __restrict__ scsh)
{
  const float4* sc4 = (const float4*)scsh;
  const float4* sh4 = (const float4*)(scsh + 128);
  int i = blockIdx.x * 256 + threadIdx.x;
  if (i >= N_NODES * 32) return;
  int c4 = i & 31;
  float4 v = ((float4*)z)[i];
  float4 s = sc4[c4], h = sh4[c4];
  v.x = fmaxf(0.f, fmaf(v.x, s.x, h.x));
  v.y = fmaxf(0.f, fmaf(v.y, s.y, h.y));
  v.z = fmaxf(0.f, fmaf(v.z, s.z, h.z));
  v.w = fmaxf(0.f, fmaf(v.w, s.w, h.w));
  ((float4*)z)[i] = v;
}

// ---------------- graph bounds: starts[g] = lower_bound(batch, g) ------------
__global__ __launch_bounds__(256) void bounds_kernel(
    const int* __restrict__ batch, int* __restrict__ starts)
{
  int g = blockIdx.x * 256 + threadIdx.x;
  if (g > NGRAPH) return;
  int lo = 0, hi = N_NODES;
  while (lo < hi) {
    int mid = (lo + hi) >> 1;
    if (batch[mid] < g) lo = mid + 1; else hi = mid;
  }
  starts[g] = lo;
}

// ---------------- fused pool+head: one block per graph -----------------------
__global__ __launch_bounds__(256) void pool_head_kernel(
    const float* __restrict__ h, const int* __restrict__ starts,
    const float* __restrict__ wlin, const float* __restrict__ blin,
    float* __restrict__ out)
{
  __shared__ float pl[256];
  __shared__ float s0[128];
  __shared__ float s1[128];
  int g = blockIdx.x;
  int tid = threadIdx.x;
  int f = tid & 127, half = tid >> 7;
  int start = starts[g], end = starts[g + 1];
  int cnt = end - start;

  float acc = 0.f;
  int r = start + half;
  for (; r + 8 <= end; r += 8) {
    float v0 = h[(size_t)r * 128 + f];
    float v1 = h[(size_t)(r + 2) * 128 + f];
    float v2 = h[(size_t)(r + 4) * 128 + f];
    float v3 = h[(size_t)(r + 6) * 128 + f];
    acc += (v0 + v1) + (v2 + v3);
  }
  for (; r < end; r += 2) acc += h[(size_t)r * 128 + f];

  pl[tid] = acc;
  __syncthreads();
  if (tid < 128) {
    float inv = 1.0f / fmaxf((float)cnt, 1.0f);
    float p = (pl[tid] + pl[tid + 128]) * inv;
    s0[tid] = p * wlin[tid * 2 + 0];
    s1[tid] = p * wlin[tid * 2 + 1];
  }
  __syncthreads();
  if (tid < 64) {
    float a0 = s0[tid] + s0[tid + 64];
    float a1 = s1[tid] + s1[tid + 64];
    for (int off = 32; off > 0; off >>= 1) {
      a0 += __shfl_down(a0, off, 64);
      a1 += __shfl_down(a1, off, 64);
    }
    if (tid == 0) {
      out[g * 2 + 0] = 1.0f / (1.0f + expf(-(a0 + blin[0])));
      out[g * 2 + 1] = 1.0f / (1.0f + expf(-(a1 + blin[1])));
    }
  }
}

extern "C" void kernel_launch(void* const* d_in, const int* in_sizes, int n_in,
                              void* d_out, int out_size, void* d_ws, size_t ws_size,
                              hipStream_t stream) {
  const float* x    = (const float*)d_in[0];
  const int*   ei   = (const int*)d_in[1];
  const int*   batch= (const int*)d_in[2];
  const float* w1l  = (const float*)d_in[3];
  const float* w1r  = (const float*)d_in[4];
  const float* b1   = (const float*)d_in[5];
  const float* g1   = (const float*)d_in[6];
  const float* be1  = (const float*)d_in[7];
  const float* w2l  = (const float*)d_in[8];
  const float* w2r  = (const float*)d_in[9];
  const float* b2   = (const float*)d_in[10];
  const float* g2   = (const float*)d_in[11];
  const float* be2  = (const float*)d_in[12];
  const float* wlin = (const float*)d_in[13];
  const float* blin = (const float*)d_in[14];
  float* out = (float*)d_out;

  char* ws = (char*)d_ws;
  int*    deg    = (int*)(ws + 0);                    // 200000 B
  ushort* csr    = (ushort*)(ws + 400000);            // 6.4 MB
  ushort* Ahi    = (ushort*)(ws + 6800000);           // 25.6 MB
  ushort* Alo    = (ushort*)(ws + 32400000);          // 25.6 MB
  float*  z      = (float*)(ws + 58000000);           // 25.6 MB
  float*  stats  = (float*)(ws + 83600000);
  float*  scsh   = stats + 256;
  int*    starts = (int*)(scsh + 256);                // 513 ints
  ushort* Wph    = (ushort*)(ws + 83866240);          // 128 KB (both layers)
  ushort* Wpl    = (ushort*)(ws + 83997312);          // 128 KB

  const int nblocks = (N_NODES * 32 + 255) / 256;     // 6250
  const int gemmblocks = (NTILES + 15) / 16;          // 196

  // ---- CSR build (dst-partitioned; also produces deg) + pre-pack + bounds ----
  fill2_kernel<<<FBLOCKS, 512, 0, stream>>>(ei, csr, deg);
  wpack_kernel<<<256, 256, 0, stream>>>(w1l, w1r, w2l, w2r, Wph, Wpl);
  bounds_kernel<<<3, 256, 0, stream>>>(batch, starts);

  // ---- layer 1 ----
  splitx_kernel<<<nblocks, 256, 0, stream>>>(x, Ahi, Alo);
  gather_kernel<<<nblocks, 256, 0, stream>>>(Ahi, Alo, csr, deg);
  hipMemsetAsync(stats, 0, 256 * 4, stream);
  gemm_kernel<<<gemmblocks, 512, 0, stream>>>(Ahi, Alo, Wph, Wpl, b1, z, stats);
  finalize_kernel<<<1, 128, 0, stream>>>(stats, g1, be1, scsh);
  bnrelu_split_kernel<<<nblocks, 256, 0, stream>>>(z, scsh, Ahi, Alo);

  // ---- layer 2 ----
  gather_kernel<<<nblocks, 256, 0, stream>>>(Ahi, Alo, csr, deg);
  hipMemsetAsync(stats, 0, 256 * 4, stream);
  gemm_kernel<<<gemmblocks, 512, 0, stream>>>(Ahi, Alo, Wph + 32768, Wpl + 32768, b2, z, stats);
  finalize_kernel<<<1, 128, 0, stream>>>(stats, g2, be2, scsh);
  bnrelu_kernel<<<nblocks, 256, 0, stream>>>(z, scsh);

  // ---- fused pool + head ----
  pool_head_kernel<<<NGRAPH, 256, 0, stream>>>(z, starts, wlin, blin, out);
}

// Round 15
// 221.064 us; speedup vs baseline: 3.1991x; 3.1991x over previous
//
#include <hip/hip_runtime.h>

#define N_NODES 50000
#define N_EDGES 800000
#define NGRAPH 512
#define MAXDEG 64
#define BN_EPS 1e-5f
#define NTILES 3125   // 50000/16 exactly

typedef __attribute__((ext_vector_type(8))) short s16x8;
typedef __attribute__((ext_vector_type(4))) float f32x4;

__device__ __forceinline__ ushort bf16_rne(float f) {
  uint u = __float_as_uint(f);
  return (ushort)((u + 0x7FFFu + ((u >> 16) & 1u)) >> 16);
}
__device__ __forceinline__ void bf16split(float f, ushort& h, ushort& l) {
  uint u = __float_as_uint(f);
  uint hb = (u + 0x7FFFu + ((u >> 16) & 1u)) & 0xFFFF0000u;
  h = (ushort)(hb >> 16);
  l = bf16_rne(f - __uint_as_float(hb));
}
__device__ __forceinline__ float bf16f(ushort h) {
  return __uint_as_float(((uint)h) << 16);
}

// ---------------- CSR fill: edge-order, int atomics. cursor ends as degree ---
// (gather clamps with min(d, MAXDEG), so overflow counts are harmless)
__global__ __launch_bounds__(256) void fill_kernel(
    const int* __restrict__ ei, int* __restrict__ cursor, ushort* __restrict__ csr)
{
  int e = blockIdx.x * 256 + threadIdx.x;
  if (e < N_EDGES) {
    int dst = ei[N_EDGES + e];
    int slot = atomicAdd(&cursor[dst], 1);
    if (slot < MAXDEG) csr[dst * MAXDEG + slot] = (ushort)ei[e];
  }
}

// ---------------- weight pre-pack: f32 [wl;wr] -> frag-ordered bf16 hi/lo ----
__global__ __launch_bounds__(256) void wpack_kernel(
    const float* __restrict__ w1l, const float* __restrict__ w1r,
    const float* __restrict__ w2l, const float* __restrict__ w2r,
    ushort* __restrict__ Wph, ushort* __restrict__ Wpl)
{
  int idx = blockIdx.x * 256 + threadIdx.x;   // < 65536
  int layer = idx >> 15;
  int e = idx & 32767;
  int j = e & 7, l = (e >> 3) & 63, t = (e >> 9) & 7, s = e >> 12;
  int k = s * 32 + ((l >> 4) << 3) + j;
  int col = t * 16 + (l & 15);
  const float* wl = layer ? w2l : w1l;
  const float* wr = layer ? w2r : w1r;
  float w = (k < 128) ? wl[k * 128 + col] : wr[(k - 128) * 128 + col];
  ushort h, lo;
  bf16split(w, h, lo);
  Wph[idx] = h;
  Wpl[idx] = lo;
}

// ---------------- split x (f32 -> bf16 hi/lo) into A[:,128:256] --------------
__global__ __launch_bounds__(256) void splitx_kernel(
    const float* __restrict__ x, ushort* __restrict__ Ahi, ushort* __restrict__ Alo)
{
  int i = blockIdx.x * 256 + threadIdx.x;
  if (i >= N_NODES * 32) return;
  int n = i >> 5, j = i & 31;
  float4 v = ((const float4*)x)[i];
  ushort4 h, l;
  bf16split(v.x, h.x, l.x); bf16split(v.y, h.y, l.y);
  bf16split(v.z, h.z, l.z); bf16split(v.w, h.w, l.w);
  *(ushort4*)(Ahi + (size_t)n * 256 + 128 + j * 4) = h;
  *(ushort4*)(Alo + (size_t)n * 256 + 128 + j * 4) = l;
}

// ---------------- gather: mean of bf16-hi rows A[:,128:256) -> A[:,0:128) ----
__global__ __launch_bounds__(256) void gather_kernel(
    ushort* Ahi, ushort* Alo,
    const ushort* __restrict__ csr, const int* __restrict__ deg)
{
  int gid = blockIdx.x * 256 + threadIdx.x;
  int n = gid >> 5, j = gid & 31;
  if (n >= N_NODES) return;
  int d = min(deg[n], MAXDEG);
  const ushort* lst = csr + n * MAXDEG;
  float ax = 0, ay = 0, az = 0, aw = 0;
  int i = 0;
  for (; i + 4 <= d; i += 4) {
    int s0 = lst[i], s1 = lst[i + 1], s2 = lst[i + 2], s3 = lst[i + 3];
    ushort4 h0 = *(const ushort4*)(Ahi + (size_t)s0 * 256 + 128 + j * 4);
    ushort4 h1 = *(const ushort4*)(Ahi + (size_t)s1 * 256 + 128 + j * 4);
    ushort4 h2 = *(const ushort4*)(Ahi + (size_t)s2 * 256 + 128 + j * 4);
    ushort4 h3 = *(const ushort4*)(Ahi + (size_t)s3 * 256 + 128 + j * 4);
    ax += (bf16f(h0.x) + bf16f(h1.x)) + (bf16f(h2.x) + bf16f(h3.x));
    ay += (bf16f(h0.y) + bf16f(h1.y)) + (bf16f(h2.y) + bf16f(h3.y));
    az += (bf16f(h0.z) + bf16f(h1.z)) + (bf16f(h2.z) + bf16f(h3.z));
    aw += (bf16f(h0.w) + bf16f(h1.w)) + (bf16f(h2.w) + bf16f(h3.w));
  }
  for (; i < d; ++i) {
    ushort4 h = *(const ushort4*)(Ahi + (size_t)lst[i] * 256 + 128 + j * 4);
    ax += bf16f(h.x); ay += bf16f(h.y); az += bf16f(h.z); aw += bf16f(h.w);
  }
  float inv = 1.0f / fmaxf((float)d, 1.0f);
  ax *= inv; ay *= inv; az *= inv; aw *= inv;
  ushort4 h, l;
  bf16split(ax, h.x, l.x); bf16split(ay, h.y, l.y);
  bf16split(az, h.z, l.z); bf16split(aw, h.w, l.w);
  *(ushort4*)(Ahi + (size_t)n * 256 + j * 4) = h;
  *(ushort4*)(Alo + (size_t)n * 256 + j * 4) = l;
}

// ---------------- MFMA GEMM: z = A(hi+lo) @ W(hi+lo) + b; BN stats -----------
__global__ __launch_bounds__(512) void gemm_kernel(
    const ushort* __restrict__ Ahi, const ushort* __restrict__ Alo,
    const ushort* __restrict__ Wph, const ushort* __restrict__ Wpl,
    const float* __restrict__ bias,
    float* __restrict__ z, float* __restrict__ stats)
{
  __shared__ uint4 lds_w[8192];           // 128 KB: [0:4096) hi, [4096:8192) lo
  __shared__ float lds_stats[256];
  int tid = threadIdx.x;

  { // coalesced vector staging of pre-packed fragments
    const uint4* gh = (const uint4*)Wph;
    const uint4* gl = (const uint4*)Wpl;
    #pragma unroll
    for (int i = 0; i < 8; ++i) lds_w[tid + i * 512] = gh[tid + i * 512];
    #pragma unroll
    for (int i = 0; i < 8; ++i) lds_w[4096 + tid + i * 512] = gl[tid + i * 512];
  }
  if (tid < 256) lds_stats[tid] = 0.f;
  __syncthreads();

  int wave = tid >> 6, lane = tid & 63;
  int col0 = lane & 15, rg = lane >> 4;
  int t0 = blockIdx.x * 16 + wave * 2;      // first tile of this wave
  bool v0 = t0 < NTILES, v1 = (t0 + 1) < NTILES;
  int r0 = min(t0 * 16 + col0, N_NODES - 1);        // clamped: no OOB loads
  int r1 = min(t0 * 16 + 16 + col0, N_NODES - 1);

  const s16x8* W8h = (const s16x8*)lds_w;
  const s16x8* W8l = W8h + 4096;
  const s16x8* pah0 = (const s16x8*)Ahi + (size_t)r0 * 32 + rg;
  const s16x8* pal0 = (const s16x8*)Alo + (size_t)r0 * 32 + rg;
  const s16x8* pah1 = (const s16x8*)Ahi + (size_t)r1 * 32 + rg;
  const s16x8* pal1 = (const s16x8*)Alo + (size_t)r1 * 32 + rg;

  f32x4 acc0[8], acc1[8];
  #pragma unroll
  for (int t = 0; t < 8; ++t) {
    float bc = bias[t * 16 + col0];
    acc0[t] = (f32x4){bc, bc, bc, bc};
    acc1[t] = acc0[t];
  }

  for (int s = 0; s < 8; ++s) {
    s16x8 ah0 = pah0[s * 4];
    s16x8 al0 = pal0[s * 4];
    s16x8 ah1 = pah1[s * 4];
    s16x8 al1 = pal1[s * 4];
    #pragma unroll
    for (int t = 0; t < 8; ++t) {
      s16x8 wh = W8h[(s * 8 + t) * 64 + lane];
      s16x8 wo = W8l[(s * 8 + t) * 64 + lane];
      acc0[t] = __builtin_amdgcn_mfma_f32_16x16x32_bf16(ah0, wh, acc0[t], 0, 0, 0);
      acc0[t] = __builtin_amdgcn_mfma_f32_16x16x32_bf16(al0, wh, acc0[t], 0, 0, 0);
      acc0[t] = __builtin_amdgcn_mfma_f32_16x16x32_bf16(ah0, wo, acc0[t], 0, 0, 0);
      acc1[t] = __builtin_amdgcn_mfma_f32_16x16x32_bf16(ah1, wh, acc1[t], 0, 0, 0);
      acc1[t] = __builtin_amdgcn_mfma_f32_16x16x32_bf16(al1, wh, acc1[t], 0, 0, 0);
      acc1[t] = __builtin_amdgcn_mfma_f32_16x16x32_bf16(ah1, wo, acc1[t], 0, 0, 0);
    }
  }

  // epilogue: C/D layout col=lane&15, row=(lane>>4)*4+reg
  float psum[8], psq[8];
  #pragma unroll
  for (int t = 0; t < 8; ++t) { psum[t] = 0.f; psq[t] = 0.f; }
  if (v0) {
    #pragma unroll
    for (int t = 0; t < 8; ++t) {
      #pragma unroll
      for (int r = 0; r < 4; ++r) {
        float v = acc0[t][r];
        z[(size_t)(t0 * 16 + rg * 4 + r) * 128 + t * 16 + col0] = v;
        psum[t] += v; psq[t] += v * v;
      }
    }
  }
  if (v1) {
    #pragma unroll
    for (int t = 0; t < 8; ++t) {
      #pragma unroll
      for (int r = 0; r < 4; ++r) {
        float v = acc1[t][r];
        z[(size_t)(t0 * 16 + 16 + rg * 4 + r) * 128 + t * 16 + col0] = v;
        psum[t] += v; psq[t] += v * v;
      }
    }
  }

  #pragma unroll
  for (int t = 0; t < 8; ++t) {
    atomicAdd(&lds_stats[t * 16 + col0], psum[t]);
    atomicAdd(&lds_stats[128 + t * 16 + col0], psq[t]);
  }
  __syncthreads();
  if (tid < 256) atomicAdd(&stats[tid], lds_stats[tid]);
}

// ---------------- BN finalize ----------------
__global__ __launch_bounds__(128) void finalize_kernel(
    const float* __restrict__ stats, const float* __restrict__ gamma,
    const float* __restrict__ beta, float* __restrict__ scsh)
{
  int f = threadIdx.x;
  const float invN = 1.0f / (float)N_NODES;
  float mu = stats[f] * invN;
  float var = stats[128 + f] * invN - mu * mu;
  var = fmaxf(var, 0.f);
  float s = gamma[f] * rsqrtf(var + BN_EPS);
  scsh[f] = s;
  scsh[128 + f] = beta[f] - mu * s;
}

// ---------------- BN+relu -> bf16 pair into A[:,128:256] (layer-1 h) --------
__global__ __launch_bounds__(256) void bnrelu_split_kernel(
    const float* __restrict__ z, const float* __restrict__ scsh,
    ushort* __restrict__ Ahi, ushort* __restrict__ Alo)
{
  const float4* sc4 = (const float4*)scsh;
  const float4* sh4 = (const float4*)(scsh + 128);
  int i = blockIdx.x * 256 + threadIdx.x;
  if (i >= N_NODES * 32) return;
  int n = i >> 5, c4 = i & 31;
  float4 v = ((const float4*)z)[i];
  float4 s = sc4[c4], hh = sh4[c4];
  v.x = fmaxf(0.f, fmaf(v.x, s.x, hh.x));
  v.y = fmaxf(0.f, fmaf(v.y, s.y, hh.y));
  v.z = fmaxf(0.f, fmaf(v.z, s.z, hh.z));
  v.w = fmaxf(0.f, fmaf(v.w, s.w, hh.w));
  ushort4 h, l;
  bf16split(v.x, h.x, l.x); bf16split(v.y, h.y, l.y);
  bf16split(v.z, h.z, l.z); bf16split(v.w, h.w, l.w);
  *(ushort4*)(Ahi + (size_t)n * 256 + 128 + c4 * 4) = h;
  *(ushort4*)(Alo + (size_t)n * 256 + 128 + c4 * 4) = l;
}

// ---------------- BN+relu in place f32 (layer-2 h, feeds pool) ---------------
__global__ __launch_bounds__(256) void bnrelu_kernel(
    float* __restrict__ z, const float* __restrict__ scsh)
{
  const float4* sc4 = (const float4*)scsh;
  const float4* sh4 = (const float4*)(scsh + 128);
  int i = blockIdx.x * 256 + threadIdx.x;
  if (i >= N_NODES * 32) return;
  int c4 = i & 31;
  float4 v = ((float4*)z)[i];
  float4 s = sc4[c4], h = sh4[c4];
  v.x = fmaxf(0.f, fmaf(v.x, s.x, h.x));
  v.y = fmaxf(0.f, fmaf(v.y, s.y, h.y));
  v.z = fmaxf(0.f, fmaf(v.z, s.z, h.z));
  v.w = fmaxf(0.f, fmaf(v.w, s.w, h.w));
  ((float4*)z)[i] = v;
}

// ---------------- graph bounds: starts[g] = lower_bound(batch, g) ------------
__global__ __launch_bounds__(256) void bounds_kernel(
    const int* __restrict__ batch, int* __restrict__ starts)
{
  int g = blockIdx.x * 256 + threadIdx.x;
  if (g > NGRAPH) return;
  int lo = 0, hi = N_NODES;
  while (lo < hi) {
    int mid = (lo + hi) >> 1;
    if (batch[mid] < g) lo = mid + 1; else hi = mid;
  }
  starts[g] = lo;
}

// ---------------- fused pool+head: one block per graph -----------------------
__global__ __launch_bounds__(256) void pool_head_kernel(
    const float* __restrict__ h, const int* __restrict__ starts,
    const float* __restrict__ wlin, const float* __restrict__ blin,
    float* __restrict__ out)
{
  __shared__ float pl[256];
  __shared__ float s0[128];
  __shared__ float s1[128];
  int g = blockIdx.x;
  int tid = threadIdx.x;
  int f = tid & 127, half = tid >> 7;
  int start = starts[g], end = starts[g + 1];
  int cnt = end - start;

  float acc = 0.f;
  int r = start + half;
  for (; r + 8 <= end; r += 8) {
    float v0 = h[(size_t)r * 128 + f];
    float v1 = h[(size_t)(r + 2) * 128 + f];
    float v2 = h[(size_t)(r + 4) * 128 + f];
    float v3 = h[(size_t)(r + 6) * 128 + f];
    acc += (v0 + v1) + (v2 + v3);
  }
  for (; r < end; r += 2) acc += h[(size_t)r * 128 + f];

  pl[tid] = acc;
  __syncthreads();
  if (tid < 128) {
    float inv = 1.0f / fmaxf((float)cnt, 1.0f);
    float p = (pl[tid] + pl[tid + 128]) * inv;
    s0[tid] = p * wlin[tid * 2 + 0];
    s1[tid] = p * wlin[tid * 2 + 1];
  }
  __syncthreads();
  if (tid < 64) {
    float a0 = s0[tid] + s0[tid + 64];
    float a1 = s1[tid] + s1[tid + 64];
    for (int off = 32; off > 0; off >>= 1) {
      a0 += __shfl_down(a0, off, 64);
      a1 += __shfl_down(a1, off, 64);
    }
    if (tid == 0) {
      out[g * 2 + 0] = 1.0f / (1.0f + expf(-(a0 + blin[0])));
      out[g * 2 + 1] = 1.0f / (1.0f + expf(-(a1 + blin[1])));
    }
  }
}

extern "C" void kernel_launch(void* const* d_in, const int* in_sizes, int n_in,
                              void* d_out, int out_size, void* d_ws, size_t ws_size,
                              hipStream_t stream) {
  const float* x    = (const float*)d_in[0];
  const int*   ei   = (const int*)d_in[1];
  const int*   batch= (const int*)d_in[2];
  const float* w1l  = (const float*)d_in[3];
  const float* w1r  = (const float*)d_in[4];
  const float* b1   = (const float*)d_in[5];
  const float* g1   = (const float*)d_in[6];
  const float* be1  = (const float*)d_in[7];
  const float* w2l  = (const float*)d_in[8];
  const float* w2r  = (const float*)d_in[9];
  const float* b2   = (const float*)d_in[10];
  const float* g2   = (const float*)d_in[11];
  const float* be2  = (const float*)d_in[12];
  const float* wlin = (const float*)d_in[13];
  const float* blin = (const float*)d_in[14];
  float* out = (float*)d_out;

  char* ws = (char*)d_ws;
  int*    cursor = (int*)(ws + 0);                    // 200000 B (ends as deg)
  ushort* csr    = (ushort*)(ws + 400000);            // 6.4 MB
  ushort* Ahi    = (ushort*)(ws + 6800000);           // 25.6 MB
  ushort* Alo    = (ushort*)(ws + 32400000);          // 25.6 MB
  float*  z      = (float*)(ws + 58000000);           // 25.6 MB
  float*  stats  = (float*)(ws + 83600000);
  float*  scsh   = stats + 256;
  int*    starts = (int*)(scsh + 256);                // 513 ints
  ushort* Wph    = (ushort*)(ws + 83866240);          // 128 KB (both layers)
  ushort* Wpl    = (ushort*)(ws + 83997312);          // 128 KB

  const int eblocks = (N_EDGES + 255) / 256;          // 3125
  const int nblocks = (N_NODES * 32 + 255) / 256;     // 6250
  const int gemmblocks = (NTILES + 15) / 16;          // 196

  // ---- CSR build (cursor doubles as degree) + pre-pack + bounds ----
  hipMemsetAsync(cursor, 0, N_NODES * sizeof(int), stream);
  fill_kernel<<<eblocks, 256, 0, stream>>>(ei, cursor, csr);
  wpack_kernel<<<256, 256, 0, stream>>>(w1l, w1r, w2l, w2r, Wph, Wpl);
  bounds_kernel<<<3, 256, 0, stream>>>(batch, starts);

  // ---- layer 1 ----
  splitx_kernel<<<nblocks, 256, 0, stream>>>(x, Ahi, Alo);
  gather_kernel<<<nblocks, 256, 0, stream>>>(Ahi, Alo, csr, cursor);
  hipMemsetAsync(stats, 0, 256 * 4, stream);
  gemm_kernel<<<gemmblocks, 512, 0, stream>>>(Ahi, Alo, Wph, Wpl, b1, z, stats);
  finalize_kernel<<<1, 128, 0, stream>>>(stats, g1, be1, scsh);
  bnrelu_split_kernel<<<nblocks, 256, 0, stream>>>(z, scsh, Ahi, Alo);

  // ---- layer 2 ----
  gather_kernel<<<nblocks, 256, 0, stream>>>(Ahi, Alo, csr, cursor);
  hipMemsetAsync(stats, 0, 256 * 4, stream);
  gemm_kernel<<<gemmblocks, 512, 0, stream>>>(Ahi, Alo, Wph + 32768, Wpl + 32768, b2, z, stats);
  finalize_kernel<<<1, 128, 0, stream>>>(stats, g2, be2, scsh);
  bnrelu_kernel<<<nblocks, 256, 0, stream>>>(z, scsh);

  // ---- fused pool + head ----
  pool_head_kernel<<<NGRAPH, 256, 0, stream>>>(z, starts, wlin, blin, out);
}